// Round 9
// baseline (295.217 us; speedup 1.0000x reference)
//
#include <hip/hip_runtime.h>
#include <hip/hip_bf16.h>

// Problem constants (reference: B=4, T=2048, D=256, H=4, DK=64, P=2T-1)
#define Bc 4
#define Tc 2048
#define Dc 256
#define Hc 4
#define DKc 64
#define Pc 4095

typedef short bf16x8 __attribute__((ext_vector_type(8)));
typedef float f32x4 __attribute__((ext_vector_type(4)));

__device__ __forceinline__ unsigned short f2bs(float x) {
    __bf16 b = (__bf16)x;                       // RNE convert
    return __builtin_bit_cast(unsigned short, b);
}
__device__ __forceinline__ float bs2f(unsigned short u) {
    unsigned int x = ((unsigned int)u) << 16;
    return __builtin_bit_cast(float, x);
}

// ---------------------------------------------------------------------------
// Shared bf16-MFMA GEMM body. outmode 2 = bf16 head-split rows (b,h,t,dk);
// outmode 3 = bf16 head-split TRANSPOSED (b,h,dk,t) — used for V so the attn
// kernel can stage V^T with vector writes instead of a per-element scatter.
// 64x64 tile, BK=64, 4 waves, 8 MFMA/wave/K-step, LDS rows 72 shorts.
// ---------------------------------------------------------------------------
__device__ __forceinline__ void gemm_body(
    const float* __restrict__ A, const float* __restrict__ Wt,
    const float* __restrict__ bias, const float* __restrict__ addv,
    unsigned short* __restrict__ outp, int M, int Tdim, float scale,
    int outmode, unsigned short* sa, unsigned short* sb)
{
    const int tid = threadIdx.x;
    const int wv = tid >> 6, lane = tid & 63;
    const int c = lane & 15, g = lane >> 4;
    const int m0 = blockIdx.x * 64, n0 = blockIdx.y * 64;
    const int tb = wv * 16;

    f32x4 acc[4];
    #pragma unroll
    for (int ct = 0; ct < 4; ct++) acc[ct] = (f32x4){0.f, 0.f, 0.f, 0.f};

    for (int k0 = 0; k0 < 256; k0 += 64) {
        if (k0) __syncthreads();
        #pragma unroll
        for (int r = 0; r < 2; r++) {
            int lin = tid + 256 * r;
            int row = lin >> 3, ch = lin & 7;
            int gm = m0 + row;
            float4 f0, f1;
            if (gm < M) {
                f0 = *(const float4*)(A + (size_t)gm * 256 + k0 + ch * 8);
                f1 = *(const float4*)(A + (size_t)gm * 256 + k0 + ch * 8 + 4);
            } else {
                f0 = make_float4(0.f, 0.f, 0.f, 0.f); f1 = f0;
            }
            unsigned short pa[8] = {f2bs(f0.x), f2bs(f0.y), f2bs(f0.z), f2bs(f0.w),
                                    f2bs(f1.x), f2bs(f1.y), f2bs(f1.z), f2bs(f1.w)};
            *(uint4*)&sa[row * 72 + ch * 8] = *(const uint4*)pa;

            float4 w0 = *(const float4*)(Wt + (size_t)(n0 + row) * 256 + k0 + ch * 8);
            float4 w1 = *(const float4*)(Wt + (size_t)(n0 + row) * 256 + k0 + ch * 8 + 4);
            unsigned short pb[8] = {f2bs(w0.x), f2bs(w0.y), f2bs(w0.z), f2bs(w0.w),
                                    f2bs(w1.x), f2bs(w1.y), f2bs(w1.z), f2bs(w1.w)};
            *(uint4*)&sb[row * 72 + ch * 8] = *(const uint4*)pb;
        }
        __syncthreads();
        #pragma unroll
        for (int kk = 0; kk < 2; kk++) {
            bf16x8 af = *(const bf16x8*)&sa[(tb + c) * 72 + kk * 32 + g * 8];
            #pragma unroll
            for (int ct = 0; ct < 4; ct++) {
                bf16x8 bf = *(const bf16x8*)&sb[(ct * 16 + c) * 72 + kk * 32 + g * 8];
                acc[ct] = __builtin_amdgcn_mfma_f32_16x16x32_bf16(af, bf, acc[ct], 0, 0, 0);
            }
        }
    }

    __syncthreads();
    const int ld = (outmode == 3) ? 66 : 72;   // 66: decollides the column gather
    #pragma unroll
    for (int ct = 0; ct < 4; ct++) {
        int n = n0 + ct * 16 + c;
        float badd = (bias ? bias[n] : 0.f) + (addv ? addv[n] : 0.f);
        #pragma unroll
        for (int r = 0; r < 4; r++)
            sa[(tb + g * 4 + r) * ld + ct * 16 + c] = f2bs((acc[ct][r] + badd) * scale);
    }
    __syncthreads();
    const int hh = n0 >> 6;
    if (outmode == 3) {
        // transposed write: thread gathers 8 consecutive-t shorts for one dk
        const int bb = m0 / Tdim, trow0 = m0 - (m0 / Tdim) * Tdim;
        #pragma unroll
        for (int r = 0; r < 2; r++) {
            int lin = tid + 256 * r;
            int dk = lin >> 3, tch = lin & 7;
            unsigned short tmp[8];
            #pragma unroll
            for (int e = 0; e < 8; e++)
                tmp[e] = sa[(tch * 8 + e) * 66 + dk];
            size_t oidx = ((size_t)(bb * Hc + hh) * DKc + dk) * Tdim + trow0 + tch * 8;
            *(uint4*)&outp[oidx] = *(const uint4*)tmp;
        }
    } else {
        #pragma unroll
        for (int r = 0; r < 2; r++) {
            int lin = tid + 256 * r;
            int row = lin >> 3, ch = lin & 7;
            int gm = m0 + row;
            if (gm >= M) continue;
            int bb = gm / Tdim, t = gm - bb * Tdim;
            size_t oidx = ((size_t)(bb * Hc + hh) * Tdim + t) * DKc + ch * 8;
            *(uint4*)&outp[oidx] = *(const uint4*)&sa[row * 72 + ch * 8];
        }
    }
}

// ---------------------------------------------------------------------------
// Fused q/k/v projections. q pre-scaled by 1/8; v written transposed.
// ---------------------------------------------------------------------------
__global__ __launch_bounds__(256) void gemm_qkv(
    const float* __restrict__ q, const float* __restrict__ k, const float* __restrict__ v,
    const float* __restrict__ Wq, const float* __restrict__ bq,
    const float* __restrict__ Wk, const float* __restrict__ bk,
    const float* __restrict__ Wv, const float* __restrict__ bv,
    const float* __restrict__ pbu,
    unsigned short* __restrict__ qo, unsigned short* __restrict__ ko,
    unsigned short* __restrict__ vo)
{
    __shared__ unsigned short sa[64 * 72];
    __shared__ unsigned short sb[64 * 72];
    const float *A, *Wt, *bias, *addv; unsigned short* outp; float scale; int mode;
    if (blockIdx.z == 0)      { A = q; Wt = Wq; bias = bq; addv = pbu;     outp = qo; scale = 0.125f; mode = 2; }
    else if (blockIdx.z == 1) { A = k; Wt = Wk; bias = bk; addv = nullptr; outp = ko; scale = 1.f;    mode = 2; }
    else                      { A = v; Wt = Wv; bias = bv; addv = nullptr; outp = vo; scale = 1.f;    mode = 3; }
    gemm_body(A, Wt, bias, addv, outp, Bc * Tc, Tc, scale, mode, sa, sb);
}

// ---------------------------------------------------------------------------
// p projection + fused dpw epilogue: dpw[h][w] = 0.125*(pbv-pbu)[h].p[h][w].
// ---------------------------------------------------------------------------
__global__ __launch_bounds__(256) void gemm_p(
    const float* __restrict__ pos_emb, const float* __restrict__ Wpos,
    const float* __restrict__ pbu, const float* __restrict__ pbv,
    unsigned short* __restrict__ ph_b, float* __restrict__ dpw)
{
    __shared__ unsigned short sa[64 * 72];
    __shared__ unsigned short sb[64 * 72];
    gemm_body(pos_emb, Wpos, nullptr, nullptr, ph_b, Pc, Pc, 1.f, 2, sa, sb);
    const int tid = threadIdx.x;
    const int m0 = blockIdx.x * 64, h = blockIdx.y;
    if (tid < 64) {
        int w = m0 + tid;
        if (w < Pc) {
            float acc = 0.f;
            #pragma unroll
            for (int dk = 0; dk < DKc; dk++)
                acc = fmaf(pbv[h * DKc + dk] - pbu[h * DKc + dk],
                           bs2f(sa[tid * 72 + dk]), acc);
            dpw[h * Pc + w] = acc * 0.125f;
        }
    }
}

// ---------------------------------------------------------------------------
// Output projection, hi/lo split for fp32-grade accuracy. Wo split inline.
// ---------------------------------------------------------------------------
__global__ __launch_bounds__(256) void gemm_out_split(
    const unsigned short* __restrict__ Ahi,
    const unsigned short* __restrict__ Alo,
    const float* __restrict__ Wo,
    const float* __restrict__ bias,
    float* __restrict__ outp, int M)
{
    __shared__ unsigned short sah[64 * 72];
    __shared__ unsigned short sal[64 * 72];
    __shared__ unsigned short sbh[64 * 72];
    __shared__ unsigned short sbl[64 * 72];
    __shared__ float sout[64 * 68];
    const int tid = threadIdx.x;
    const int wv = tid >> 6, lane = tid & 63;
    const int c = lane & 15, g = lane >> 4;
    const int m0 = blockIdx.x * 64, n0 = blockIdx.y * 64;
    const int tb = wv * 16;

    f32x4 acc[4];
    #pragma unroll
    for (int ct = 0; ct < 4; ct++) acc[ct] = (f32x4){0.f, 0.f, 0.f, 0.f};

    for (int k0 = 0; k0 < 256; k0 += 64) {
        if (k0) __syncthreads();
        #pragma unroll
        for (int r = 0; r < 2; r++) {
            int lin = tid + 256 * r;
            int row = lin >> 3, ch = lin & 7;
            size_t asrc = (size_t)(m0 + row) * 256 + k0 + ch * 8;
            *(uint4*)&sah[row * 72 + ch * 8] = *(const uint4*)(Ahi + asrc);
            *(uint4*)&sal[row * 72 + ch * 8] = *(const uint4*)(Alo + asrc);
            float4 w0 = *(const float4*)(Wo + (size_t)(n0 + row) * 256 + k0 + ch * 8);
            float4 w1 = *(const float4*)(Wo + (size_t)(n0 + row) * 256 + k0 + ch * 8 + 4);
            float we[8] = {w0.x, w0.y, w0.z, w0.w, w1.x, w1.y, w1.z, w1.w};
            unsigned short phi[8], plo[8];
            #pragma unroll
            for (int e = 0; e < 8; e++) {
                unsigned short hi = f2bs(we[e]);
                phi[e] = hi;
                plo[e] = f2bs(we[e] - bs2f(hi));
            }
            *(uint4*)&sbh[row * 72 + ch * 8] = *(const uint4*)phi;
            *(uint4*)&sbl[row * 72 + ch * 8] = *(const uint4*)plo;
        }
        __syncthreads();
        #pragma unroll
        for (int kk = 0; kk < 2; kk++) {
            bf16x8 ah = *(const bf16x8*)&sah[(tb + c) * 72 + kk * 32 + g * 8];
            bf16x8 al = *(const bf16x8*)&sal[(tb + c) * 72 + kk * 32 + g * 8];
            #pragma unroll
            for (int ct = 0; ct < 4; ct++) {
                bf16x8 bh = *(const bf16x8*)&sbh[(ct * 16 + c) * 72 + kk * 32 + g * 8];
                bf16x8 bl = *(const bf16x8*)&sbl[(ct * 16 + c) * 72 + kk * 32 + g * 8];
                acc[ct] = __builtin_amdgcn_mfma_f32_16x16x32_bf16(ah, bh, acc[ct], 0, 0, 0);
                acc[ct] = __builtin_amdgcn_mfma_f32_16x16x32_bf16(ah, bl, acc[ct], 0, 0, 0);
                acc[ct] = __builtin_amdgcn_mfma_f32_16x16x32_bf16(al, bh, acc[ct], 0, 0, 0);
            }
        }
    }

    __syncthreads();
    #pragma unroll
    for (int ct = 0; ct < 4; ct++) {
        float b = bias[n0 + ct * 16 + c];
        #pragma unroll
        for (int r = 0; r < 4; r++)
            sout[(tb + g * 4 + r) * 68 + ct * 16 + c] = acc[ct][r] + b;
    }
    __syncthreads();
    #pragma unroll
    for (int r = 0; r < 4; r++) {
        int lin = tid + 256 * r;
        int row = lin >> 4, c4 = lin & 15;
        float4 v = *(const float4*)&sout[row * 68 + c4 * 4];
        *(float4*)&outp[(size_t)(m0 + row) * 256 + n0 + c4 * 4] = v;
    }
}

// ---------------------------------------------------------------------------
// MFMA flash attention, QT=128, LDS-minimal:
//  - K in LDS (T14 reg-prefetched), V^T in LDS (b128 staged from transposed
//    global layout), P/dpw read DIRECT from global (L1/L2-resident window),
//    Q frags from global once, BD diagonal gather via __shfl (no sbdw LDS).
// LDS 37 KB. q and dpw pre-scaled by 1/8.
// ---------------------------------------------------------------------------
#define NTILES (Tc / 64)

__global__ __launch_bounds__(512) void attn_mfma(
    const unsigned short* __restrict__ qu,   // (B,H,T,DK) bf16, = (q+pbu)/8
    const unsigned short* __restrict__ kh,   // (B,H,T,DK) bf16
    const unsigned short* __restrict__ vt,   // (B,H,DK,T) bf16  TRANSPOSED
    const unsigned short* __restrict__ ph,   // (H,P,DK)  bf16
    const float* __restrict__ dpw_g,         // (H,P), pre-scaled by 1/8
    const int*   __restrict__ mask,          // (B,T)
    unsigned short* __restrict__ xhi,        // (B,T,D) bf16 hi
    unsigned short* __restrict__ xlo)        // (B,T,D) bf16 lo
{
    __shared__ unsigned short sk[64 * 72];    // 9.2 KB
    __shared__ unsigned short svt[64 * 72];   // 9.2 KB  [dk][t ^ swz]
    __shared__ unsigned short sp[128 * 72];   // 18.4 KB probs, wave-private rows
    __shared__ float smask[64];

    const int tid = threadIdx.x;
    const int wv = tid >> 6;
    const int lane = tid & 63;
    const int c = lane & 15, g = lane >> 4;
    const int bh = blockIdx.x, b = bh >> 2, h = bh & 3;
    const int t0 = blockIdx.y * 128;
    const int tb = wv * 16;
    const int base0 = Tc - 128 - t0;          // window base at kt=0, >= 0

    const unsigned short* qbase = qu + ((size_t)bh * Tc + t0) * DKc;
    const unsigned short* kbase = kh + (size_t)bh * Tc * DKc;
    const unsigned short* vtbase = vt + (size_t)bh * DKc * Tc;
    const unsigned short* pbase = ph + (size_t)h * Pc * DKc;
    const float* dpwbase = dpw_g + h * Pc;

    const int srow = tid >> 3, sch = tid & 7;   // [0,64) x [0,8)

    // ---- Q fragments once from global
    bf16x8 qf0 = *(const bf16x8*)(qbase + (size_t)(tb + c) * DKc + g * 8);
    bf16x8 qf1 = *(const bf16x8*)(qbase + (size_t)(tb + c) * DKc + 32 + g * 8);

    // ---- stage tile 0: K rows, V^T rows (swizzled col), mask
    *(uint4*)&sk[srow * 72 + sch * 8] =
        *(const uint4*)(kbase + (size_t)srow * DKc + sch * 8);
    *(uint4*)&svt[srow * 72 + ((sch * 8) ^ ((srow >> 3) << 3))] =
        *(const uint4*)(vtbase + (size_t)srow * Tc + sch * 8);
    if (tid < 64) smask[tid] = (mask[b * Tc + tid] == 0) ? -1e9f : 0.f;
    __syncthreads();

    // ---- T14: issue tile-1 loads into regs
    uint4 kreg, vreg; int mreg = 1;
    kreg = *(const uint4*)(kbase + (size_t)(64 + srow) * DKc + sch * 8);
    vreg = *(const uint4*)(vtbase + (size_t)srow * Tc + 64 + sch * 8);
    if (tid < 64) mreg = mask[b * Tc + 64 + tid];

    f32x4 O[4];
    #pragma unroll
    for (int ct = 0; ct < 4; ct++) O[ct] = (f32x4){0.f, 0.f, 0.f, 0.f};
    float mrow[4], lrow[4];
    #pragma unroll
    for (int r = 0; r < 4; r++) { mrow[r] = -3.0e38f; lrow[r] = 0.f; }

    for (int kt = 0; kt < NTILES; kt++) {
        const int relb = base0 + kt * 64;

        __builtin_amdgcn_s_setprio(1);
        // ---- AC: 16x64 score stripe (K from LDS)
        f32x4 sac[4];
        #pragma unroll
        for (int ct = 0; ct < 4; ct++) {
            f32x4 acc = (f32x4){0.f, 0.f, 0.f, 0.f};
            bf16x8 kf0 = *(const bf16x8*)&sk[(ct * 16 + c) * 72 + g * 8];
            bf16x8 kf1 = *(const bf16x8*)&sk[(ct * 16 + c) * 72 + (4 + g) * 8];
            acc = __builtin_amdgcn_mfma_f32_16x16x32_bf16(qf0, kf0, acc, 0, 0, 0);
            acc = __builtin_amdgcn_mfma_f32_16x16x32_bf16(qf1, kf1, acc, 0, 0, 0);
            sac[ct] = acc;
        }

        // ---- BD: 16x80 banded stripe, P + dpw DIRECT from global (L1/L2)
        const int wstart = 112 - tb;
        f32x4 accB[5];
        #pragma unroll
        for (int wt = 0; wt < 5; wt++) {
            int pabs = relb + wstart + wt * 16 + c;
            if (pabs > Pc - 1) pabs = Pc - 1;      // row Pc-1 pad never consumed
            const unsigned short* prow = pbase + (size_t)pabs * DKc;
            bf16x8 pf0 = *(const bf16x8*)(prow + g * 8);
            bf16x8 pf1 = *(const bf16x8*)(prow + 32 + g * 8);
            f32x4 a = (f32x4){0.f, 0.f, 0.f, 0.f};
            a = __builtin_amdgcn_mfma_f32_16x16x32_bf16(qf0, pf0, a, 0, 0, 0);
            a = __builtin_amdgcn_mfma_f32_16x16x32_bf16(qf1, pf1, a, 0, 0, 0);
            float dpwv = dpwbase[pabs];
            a[0] += dpwv; a[1] += dpwv; a[2] += dpwv; a[3] += dpwv;
            accB[wt] = a;
        }
        __builtin_amdgcn_s_setprio(0);

        // ---- diagonal gather via shfl: BD[tt][f], f = jc - tt + 15,
        //      producer lane = 16g + (f&15), stripe reg = accB[f>>4][r]
        float sreg[4][4];
        #pragma unroll
        for (int r = 0; r < 4; r++) {
            int idx = c - 4 * g - r + 15;          // in [0,30]
            int src = 16 * g + (idx & 15);
            bool hi = (idx >> 4) != 0;
            float b0 = __shfl(accB[0][r], src);
            float b1 = __shfl(accB[1][r], src);
            float b2 = __shfl(accB[2][r], src);
            float b3 = __shfl(accB[3][r], src);
            float b4 = __shfl(accB[4][r], src);
            sreg[0][r] = sac[0][r] + (hi ? b1 : b0);
            sreg[1][r] = sac[1][r] + (hi ? b2 : b1);
            sreg[2][r] = sac[2][r] + (hi ? b3 : b2);
            sreg[3][r] = sac[3][r] + (hi ? b4 : b3);
        }
        #pragma unroll
        for (int ct = 0; ct < 4; ct++) {
            float madd = smask[ct * 16 + c];
            #pragma unroll
            for (int r = 0; r < 4; r++) sreg[ct][r] += madd;
        }

        // ---- online softmax
        float tmax[4], tsum[4];
        #pragma unroll
        for (int r = 0; r < 4; r++)
            tmax[r] = fmaxf(fmaxf(sreg[0][r], sreg[1][r]), fmaxf(sreg[2][r], sreg[3][r]));
        #pragma unroll
        for (int off = 1; off < 16; off <<= 1)
            #pragma unroll
            for (int r = 0; r < 4; r++)
                tmax[r] = fmaxf(tmax[r], __shfl_xor(tmax[r], off));

        float mnew[4], scl[4];
        #pragma unroll
        for (int r = 0; r < 4; r++) {
            mnew[r] = fmaxf(mrow[r], tmax[r]);
            scl[r] = __expf(mrow[r] - mnew[r]);
        }
        float pr[4][4];
        #pragma unroll
        for (int r = 0; r < 4; r++) {
            #pragma unroll
            for (int ct = 0; ct < 4; ct++)
                pr[ct][r] = __expf(sreg[ct][r] - mnew[r]);
            tsum[r] = (pr[0][r] + pr[1][r]) + (pr[2][r] + pr[3][r]);
        }
        #pragma unroll
        for (int off = 1; off < 16; off <<= 1)
            #pragma unroll
            for (int r = 0; r < 4; r++)
                tsum[r] += __shfl_xor(tsum[r], off);
        #pragma unroll
        for (int r = 0; r < 4; r++) {
            lrow[r] = lrow[r] * scl[r] + tsum[r];
            mrow[r] = mnew[r];
        }
        #pragma unroll
        for (int ct = 0; ct < 4; ct++) {
            f32x4 o = O[ct];
            o[0] *= scl[0]; o[1] *= scl[1]; o[2] *= scl[2]; o[3] *= scl[3];
            O[ct] = o;
        }

        // ---- P -> bf16 LDS (wave-private rows), then PV (V^T from LDS)
        #pragma unroll
        for (int ct = 0; ct < 4; ct++)
            #pragma unroll
            for (int r = 0; r < 4; r++)
                sp[(tb + g * 4 + r) * 72 + ct * 16 + c] = f2bs(pr[ct][r]);

        __builtin_amdgcn_s_setprio(1);
        #pragma unroll
        for (int js = 0; js < 2; js++) {
            bf16x8 pfrag = *(const bf16x8*)&sp[(tb + c) * 72 + (js * 4 + g) * 8];
            #pragma unroll
            for (int ct = 0; ct < 4; ct++) {
                int dk = ct * 16 + c;
                int tcol = (js * 32 + g * 8) ^ ((dk >> 3) << 3);
                bf16x8 vf = *(const bf16x8*)&svt[dk * 72 + tcol];
                O[ct] = __builtin_amdgcn_mfma_f32_16x16x32_bf16(pfrag, vf, O[ct], 0, 0, 0);
            }
        }
        __builtin_amdgcn_s_setprio(0);

        if (kt == NTILES - 1) break;

        // ---- staging for tile kt+1 (regs issued one phase ago)
        __syncthreads();
        *(uint4*)&sk[srow * 72 + sch * 8] = kreg;
        *(uint4*)&svt[srow * 72 + ((sch * 8) ^ ((srow >> 3) << 3))] = vreg;
        if (tid < 64) smask[tid] = (mreg == 0) ? -1e9f : 0.f;
        __syncthreads();

        // ---- issue loads for tile kt+2
        if (kt + 2 < NTILES) {
            const int j0n = (kt + 2) * 64;
            kreg = *(const uint4*)(kbase + (size_t)(j0n + srow) * DKc + sch * 8);
            vreg = *(const uint4*)(vtbase + (size_t)srow * Tc + j0n + sch * 8);
            if (tid < 64) mreg = mask[b * Tc + j0n + tid];
        }
    }

    // ---- epilogue: normalize, write bf16 hi + lo residual
    float invl[4];
    #pragma unroll
    for (int r = 0; r < 4; r++)
        invl[r] = (lrow[r] > 0.f) ? 1.f / lrow[r] : 0.f;
    #pragma unroll
    for (int ct = 0; ct < 4; ct++)
        #pragma unroll
        for (int r = 0; r < 4; r++) {
            size_t idx = ((size_t)(b * Tc + t0 + tb + g * 4 + r)) * Dc + h * DKc + ct * 16 + c;
            float v = O[ct][r] * invl[r];
            unsigned short hi = f2bs(v);
            xhi[idx] = hi;
            xlo[idx] = f2bs(v - bs2f(hi));
        }
}

// ---------------------------------------------------------------------------
extern "C" void kernel_launch(void* const* d_in, const int* in_sizes, int n_in,
                              void* d_out, int out_size, void* d_ws, size_t ws_size,
                              hipStream_t stream) {
    const float* query   = (const float*)d_in[0];
    const float* key_    = (const float*)d_in[1];
    const float* value   = (const float*)d_in[2];
    const float* pos_emb = (const float*)d_in[3];
    const int*   mask    = (const int*)d_in[4];
    const float* Wq  = (const float*)d_in[5];
    const float* bq  = (const float*)d_in[6];
    const float* Wk  = (const float*)d_in[7];
    const float* bk  = (const float*)d_in[8];
    const float* Wv  = (const float*)d_in[9];
    const float* bv  = (const float*)d_in[10];
    const float* Wpos = (const float*)d_in[11];
    const float* pbu = (const float*)d_in[12];
    const float* pbv = (const float*)d_in[13];
    const float* Wo  = (const float*)d_in[14];
    const float* bo  = (const float*)d_in[15];
    float* out = (float*)d_out;

    // Workspace layout (~22 MB)
    const size_t NQ = (size_t)Bc * Hc * Tc * DKc;       // 2,097,152
    unsigned short* qu_b = (unsigned short*)d_ws;
    unsigned short* kh_b = qu_b + NQ;
    unsigned short* vt_b = kh_b + NQ;                   // (b,h,dk,t) transposed
    unsigned short* ph_b = vt_b + NQ;                   // 1,048,576 slot
    unsigned short* xhi  = ph_b + 1048576;
    unsigned short* xlo  = xhi + NQ;
    float* dpw = (float*)(xlo + NQ);                    // 16,380 floats

    gemm_qkv<<<dim3(128, 4, 3), dim3(256), 0, stream>>>(query, key_, value,
        Wq, bq, Wk, bk, Wv, bv, pbu, qu_b, kh_b, vt_b);
    gemm_p<<<dim3(64, 4), dim3(256), 0, stream>>>(pos_emb, Wpos, pbu, pbv, ph_b, dpw);
    attn_mfma<<<dim3(Bc * Hc, Tc / 128), dim3(512), 0, stream>>>(
        qu_b, kh_b, vt_b, ph_b, dpw, mask, xhi, xlo);
    gemm_out_split<<<dim3(128, 4), dim3(256), 0, stream>>>(xhi, xlo, Wo, bo, out, Bc * Tc);
}